// Round 1
// baseline (11932.610 us; speedup 1.0000x reference)
//
#include <hip/hip_runtime.h>
#include <math.h>

// resRNN forward: N=256 sequences, L=1024 steps, inp=521 (=8 x + 1 storage + 512 hx),
// HID=512, OUT=1.
// Design (round 1): one block per 2 batch elements (128 blocks x 512 threads).
// Batch elements are independent -> no inter-block communication; the full
// recurrence runs inside one kernel. Thread j owns hidden column j for both
// batch elements; W1 column j is streamed from L2 each step (1.07 MB/block/step,
// amortized over 2 batch accumulators). inp vector lives in LDS (broadcast reads).

constexpr int kN   = 256;
constexpr int kL   = 1024;
constexpr int kHin = 8;
constexpr int kHid = 512;
constexpr int kInp = kHin + 1 + kHid;  // 521
constexpr int kBlk = 512;              // threads per block
constexpr int kBpb = 2;                // batch elements per block

__global__ __launch_bounds__(kBlk, 2)
void resrnn_fwd(const float* __restrict__ x, const float* __restrict__ W1,
                const float* __restrict__ b1, const float* __restrict__ W2,
                const float* __restrict__ b2, float* __restrict__ out) {
  // inp layout: [0..7]=x_t, [8]=s_t, [9..520]=hx_{t-1}
  __shared__ __align__(16) float in0[kInp + 3];
  __shared__ __align__(16) float in1[kInp + 3];
  __shared__ float red[8][2];

  const int j  = threadIdx.x;          // 0..511: hidden column
  const int n0 = blockIdx.x * kBpb;
  const int n1 = n0 + 1;

  const float b2v = b2[0];
  const float w2j = W2[j];
  const float b1j = b1[j];

  float* const outp = out;                        // (N,L,1) flat
  float* const stor = out + (size_t)kN * kL;      // (N,L,1) flat, second tuple elem

  const float* x0 = x + (size_t)n0 * kL * kHin;
  const float* x1 = x + (size_t)n1 * kL * kHin;

  // ---- init: hx = 0, s_0 = 0 + x_0[0] - 0 ----
  in0[kHin + 1 + j] = 0.f;
  in1[kHin + 1 + j] = 0.f;
  float s0 = x0[0];
  float s1 = x1[0];
  if (j < 8)            in0[j]     = x0[j];
  else if (j < 16)      in1[j - 8] = x1[j - 8];
  if (j == 16)          in0[kHin]  = s0;
  if (j == 17)          in1[kHin]  = s1;
  if (j == 0) {
    stor[n0 * kL] = s0;
    stor[n1 * kL] = s1;
  }
  __syncthreads();

  const float* wj = W1 + j;  // column j, stride kHid

  for (int t = 0; t < kL; ++t) {
    // ---- hx_new[j] = tanh(b1[j] + sum_k inp[k] * W1[k][j]) for both batches ----
    float a0 = b1j, a1 = b1j;   // fma chain A
    float c0 = 0.f, c1 = 0.f;   // fma chain B (ILP)
    const float* wk = wj;
    #pragma unroll 4
    for (int k = 0; k < 520; k += 4) {
      const float4 va = *reinterpret_cast<const float4*>(&in0[k]);
      const float4 vb = *reinterpret_cast<const float4*>(&in1[k]);
      const float w0 = wk[0];
      const float w1 = wk[kHid];
      const float w2 = wk[2 * kHid];
      const float w3 = wk[3 * kHid];
      a0 = fmaf(va.x, w0, a0);  a1 = fmaf(vb.x, w0, a1);
      c0 = fmaf(va.y, w1, c0);  c1 = fmaf(vb.y, w1, c1);
      a0 = fmaf(va.z, w2, a0);  a1 = fmaf(vb.z, w2, a1);
      c0 = fmaf(va.w, w3, c0);  c1 = fmaf(vb.w, w3, c1);
      wk += 4 * kHid;
    }
    {  // tail k = 520
      const float wl = wj[520 * kHid];
      a0 = fmaf(in0[520], wl, a0);
      a1 = fmaf(in1[520], wl, a1);
    }
    const float h0 = tanhf(a0 + c0);
    const float h1 = tanhf(a1 + c1);

    // ---- out = hx_new . W2 + b2 : wave shuffle reduce, then LDS combine ----
    float p0 = h0 * w2j;
    float p1 = h1 * w2j;
    #pragma unroll
    for (int off = 32; off > 0; off >>= 1) {
      p0 += __shfl_down(p0, off, 64);
      p1 += __shfl_down(p1, off, 64);
    }
    const int lane = j & 63, wid = j >> 6;
    if (lane == 0) { red[wid][0] = p0; red[wid][1] = p1; }
    __syncthreads();  // barrier A: all inp reads done; red[] populated

    float d0 = 0.f, d1 = 0.f;
    #pragma unroll
    for (int w = 0; w < 8; ++w) { d0 += red[w][0]; d1 += red[w][1]; }
    const float o0 = d0 + b2v;  // identical in every thread
    const float o1 = d1 + b2v;
    if (j == 0) {
      outp[n0 * kL + t] = o0;
      outp[n1 * kL + t] = o1;
    }

    // ---- prepare step t+1: hx, x, s = s + x_{t+1}[0] - out_t ----
    in0[kHin + 1 + j] = h0;
    in1[kHin + 1 + j] = h1;
    if (t + 1 < kL) {
      const float* xr0 = x0 + (size_t)(t + 1) * kHin;
      const float* xr1 = x1 + (size_t)(t + 1) * kHin;
      s0 += xr0[0] - o0;  // replicated identically across threads
      s1 += xr1[0] - o1;
      if (j < 8)       in0[j]     = xr0[j];
      else if (j < 16) in1[j - 8] = xr1[j - 8];
      if (j == 16)     in0[kHin]  = s0;
      if (j == 17)     in1[kHin]  = s1;
      if (j == 0) {
        stor[n0 * kL + t + 1] = s0;
        stor[n1 * kL + t + 1] = s1;
      }
    }
    __syncthreads();  // barrier B: next-step inp fully staged
  }
}

extern "C" void kernel_launch(void* const* d_in, const int* in_sizes, int n_in,
                              void* d_out, int out_size, void* d_ws, size_t ws_size,
                              hipStream_t stream) {
  const float* x  = (const float*)d_in[0];
  const float* W1 = (const float*)d_in[1];
  const float* b1 = (const float*)d_in[2];
  const float* W2 = (const float*)d_in[3];
  const float* b2 = (const float*)d_in[4];
  float* out = (float*)d_out;

  dim3 grid(kN / kBpb);   // 128 blocks
  dim3 block(kBlk);       // 512 threads
  hipLaunchKernelGGL(resrnn_fwd, grid, block, 0, stream, x, W1, b1, W2, b2, out);
}